// Round 6
// baseline (265.269 us; speedup 1.0000x reference)
//
#include <hip/hip_runtime.h>
#include <cstdint>

#define NEG_INF (-__builtin_inff())

static constexpr int H = 2048;
static constexpr int W = 2048;
static constexpr int STR = 248;      // counted cols per wave stripe (9 stripes)
static constexpr int RC  = 16;       // rows counted per wave
static constexpr int NR  = RC + 6;   // 22 rows held in registers
static constexpr int NCH = H / RC;   // 128 row-chunks per image
static constexpr int GY  = NCH / 4;  // 32 blocks in y (4 waves/block)
static constexpr int NBLK = 9 * GY * 8;  // 2304 blocks per pass

struct F4 { float x, y, z, w; };

__device__ __forceinline__ F4 ld4(const float* __restrict__ p) {
    float4 v = *reinterpret_cast<const float4*>(p);
    return {v.x, v.y, v.z, v.w};
}

__device__ __forceinline__ float fmax3(float a, float b, float c) {
    return fmaxf(fmaxf(a, b), c);
}

// 7-window maxes for 4 consecutive outputs from 10 inputs a0..a9 (verified r1-r5)
__device__ __forceinline__ void hmax7_4(float a0, float a1, float a2,
                                        float a3, float a4, float a5, float a6,
                                        float a7, float a8, float a9,
                                        float& m0, float& m1, float& m2, float& m3) {
    float p23 = fmaxf(a2, a3), p45 = fmaxf(a4, a5), p67 = fmaxf(a6, a7);
    float q25 = fmaxf(p23, p45), q47 = fmaxf(p45, p67);
    m0 = fmax3(fmaxf(a0, a1), q25, a6);
    m1 = fmax3(fmaxf(a1, a2), fmax3(a3, a4, a5), fmaxf(a6, a7));
    m2 = fmax3(p23, q47, a8);
    m3 = fmax3(fmaxf(a3, a4), fmax3(a5, a6, a7), fmaxf(a8, a9));
}

struct Setup {
    int c4, cA, cmask, imask;
    float pad0, pad1, pad2, pad3;
};

__device__ __forceinline__ Setup make_setup(int sIdx, int lane) {
    Setup s;
    const int cstart = sIdx * STR;
    s.c4 = cstart - 4 + lane * 4;
    s.cA = min(max(s.c4, 0), W - 4);
    s.cmask = 0; s.imask = 0;
#pragma unroll
    for (int k = 0; k < 4; ++k) {
        const int col = s.c4 + k;
        if (col >= cstart && col < cstart + STR && col < W) s.cmask |= 1 << k;
        if (col >= 0 && col < W)                            s.imask |= 1 << k;
    }
    s.pad0 = ((s.c4 + 0) < 3 || (s.c4 + 0) > W - 4) ? 0.f : NEG_INF;
    s.pad1 = ((s.c4 + 1) < 3 || (s.c4 + 1) > W - 4) ? 0.f : NEG_INF;
    s.pad2 = ((s.c4 + 2) < 3 || (s.c4 + 2) > W - 4) ? 0.f : NEG_INF;
    s.pad3 = ((s.c4 + 3) < 3 || (s.c4 + 3) > W - 4) ? 0.f : NEG_INF;
    return s;
}

// Load NR rows into registers with max MLP, then mask out-of-image cols/rows.
__device__ __forceinline__ void load_rows(const float* __restrict__ img,
                                          int r0, const Setup& s, F4 (&cur)[NR]) {
#pragma unroll
    for (int t = 0; t < NR; ++t) {
        const int irc = min(max(r0 - 3 + t, 0), H - 1);
        cur[t] = ld4(img + (size_t)irc * W + s.cA);
    }
#pragma unroll
    for (int t = 0; t < NR; ++t)
        asm volatile("" : "+v"(cur[t].x), "+v"(cur[t].y), "+v"(cur[t].z), "+v"(cur[t].w));
    if (s.imask != 0xF) {
#pragma unroll
        for (int t = 0; t < NR; ++t) {
            if (!(s.imask & 1)) cur[t].x = NEG_INF;
            if (!(s.imask & 2)) cur[t].y = NEG_INF;
            if (!(s.imask & 4)) cur[t].z = NEG_INF;
            if (!(s.imask & 8)) cur[t].w = NEG_INF;
        }
    }
#pragma unroll
    for (int t = 0; t < NR; ++t) {
        if (t < 3 || t >= NR - 3) {          // only prologue/epilogue rows can be OOB
            const int ir = r0 - 3 + t;
            if (ir < 0 || ir >= H) cur[t] = {NEG_INF, NEG_INF, NEG_INF, NEG_INF};
        }
    }
}

// blk linear id: (b*GY + by)*9 + sIdx  -> per-image contiguous ranges of 288
__device__ __forceinline__ int blk_id() {
    return (blockIdx.z * GY + blockIdx.y) * 9 + blockIdx.x;
}

// Pass 1: per-block partial sums of dil_h and dil_v (no atomics, unique slots).
__global__ __launch_bounds__(256) void k_sums(const float* __restrict__ x,
                                              double* __restrict__ sums) {
    const int tid = threadIdx.x, lane = tid & 63, wid = tid >> 6;
    const int sIdx = blockIdx.x;
    const int rr   = blockIdx.y * 4 + wid;
    const int b    = blockIdx.z;
    const int r0   = rr * RC;
    const float* img = x + (size_t)b * H * W;
    const Setup s = make_setup(sIdx, lane);

    F4 cur[NR];
    load_rows(img, r0, s, cur);

    float shf = 0.f, svf = 0.f;
#pragma unroll
    for (int t = 3; t < 3 + RC; ++t) {
        F4 c = cur[t];
        float la1 = __shfl_up(c.y, 1), la2 = __shfl_up(c.z, 1), la3 = __shfl_up(c.w, 1);
        float ra0 = __shfl_down(c.x, 1), ra1 = __shfl_down(c.y, 1), ra2 = __shfl_down(c.z, 1);
        float m0, m1, m2, m3;
        hmax7_4(la1, la2, la3, c.x, c.y, c.z, c.w, ra0, ra1, ra2, m0, m1, m2, m3);
        m0 = fmaxf(m0, s.pad0); m1 = fmaxf(m1, s.pad1);
        m2 = fmaxf(m2, s.pad2); m3 = fmaxf(m3, s.pad3);
        shf += ((s.cmask & 1) ? m0 : 0.f) + ((s.cmask & 2) ? m1 : 0.f)
             + ((s.cmask & 4) ? m2 : 0.f) + ((s.cmask & 8) ? m3 : 0.f);
    }
#pragma unroll
    for (int jj = 0; jj < RC; ++jj) {
        const int j = r0 + jj;
        const float rpad = (j < 3 || j > H - 4) ? 0.f : NEG_INF;
        float mx = fmax3(fmax3(cur[jj].x, cur[jj+1].x, cur[jj+2].x),
                         fmax3(cur[jj+3].x, cur[jj+4].x, cur[jj+5].x), cur[jj+6].x);
        float my = fmax3(fmax3(cur[jj].y, cur[jj+1].y, cur[jj+2].y),
                         fmax3(cur[jj+3].y, cur[jj+4].y, cur[jj+5].y), cur[jj+6].y);
        float mz = fmax3(fmax3(cur[jj].z, cur[jj+1].z, cur[jj+2].z),
                         fmax3(cur[jj+3].z, cur[jj+4].z, cur[jj+5].z), cur[jj+6].z);
        float mw = fmax3(fmax3(cur[jj].w, cur[jj+1].w, cur[jj+2].w),
                         fmax3(cur[jj+3].w, cur[jj+4].w, cur[jj+5].w), cur[jj+6].w);
        mx = fmaxf(mx, rpad); my = fmaxf(my, rpad);
        mz = fmaxf(mz, rpad); mw = fmaxf(mw, rpad);
        svf += ((s.cmask & 1) ? mx : 0.f) + ((s.cmask & 2) ? my : 0.f)
             + ((s.cmask & 4) ? mz : 0.f) + ((s.cmask & 8) ? mw : 0.f);
    }

    double sh = (double)shf, sv = (double)svf;
    for (int off = 32; off > 0; off >>= 1) {
        sh += __shfl_down(sh, off);
        sv += __shfl_down(sv, off);
    }
    __shared__ double sdh[4], sdv[4];
    if (lane == 0) { sdh[wid] = sh; sdv[wid] = sv; }
    __syncthreads();
    if (tid == 0) {
        const int blk = blk_id();
        sums[blk]        = sdh[0] + sdh[1] + sdh[2] + sdh[3];
        sums[NBLK + blk] = sdv[0] + sdv[1] + sdv[2] + sdv[3];
    }
}

// Fold 288 block-partials per (orient,image) -> threshold. 16 pairs x 16 threads.
__global__ void k_thr(const double* __restrict__ sums, float* __restrict__ thr) {
    const int tid = threadIdx.x;           // 0..255
    const int pair = tid >> 4, l16 = tid & 15;
    const double* base = sums + (pair < 8 ? pair * 288 : NBLK + (pair - 8) * 288);
    double a = 0.0;
#pragma unroll
    for (int k = 0; k < 18; ++k) a += base[l16 + k * 16];
    a += __shfl_down(a, 8);
    a += __shfl_down(a, 4);
    a += __shfl_down(a, 2);
    a += __shfl_down(a, 1);
    if (l16 == 0) thr[pair] = (float)(a * (1.0 / ((double)H * (double)W)));
}

// Pass 2 fused: both orientation counts from one register-resident row window.
__global__ __launch_bounds__(256) void k_counts(const float* __restrict__ x,
                                                const float* __restrict__ thr,
                                                unsigned int* __restrict__ cnts) {
    const int tid = threadIdx.x, lane = tid & 63, wid = tid >> 6;
    const int sIdx = blockIdx.x;
    const int rr   = blockIdx.y * 4 + wid;
    const int b    = blockIdx.z;
    const int r0   = rr * RC;
    const float* img = x + (size_t)b * H * W;
    const Setup s = make_setup(sIdx, lane);
    const float thr1 = thr[b], thr2 = thr[8 + b];

    F4 cur[NR];
    load_rows(img, r0, s, cur);

    // ---- orientation 1: bi bits over rows t in [1, NR-1); vertical 3-open ----
    unsigned bc0 = 0, bc1 = 0, bc2 = 0, bc3 = 0;
#pragma unroll
    for (int t = 1; t < NR - 1; ++t) {
        F4 c = cur[t];
        float la1 = __shfl_up(c.y, 1), la2 = __shfl_up(c.z, 1), la3 = __shfl_up(c.w, 1);
        float ra0 = __shfl_down(c.x, 1), ra1 = __shfl_down(c.y, 1), ra2 = __shfl_down(c.z, 1);
        float m0, m1, m2, m3;
        hmax7_4(la1, la2, la3, c.x, c.y, c.z, c.w, ra0, ra1, ra2, m0, m1, m2, m3);
        m0 = fmaxf(m0, s.pad0); m1 = fmaxf(m1, s.pad1);
        m2 = fmaxf(m2, s.pad2); m3 = fmaxf(m3, s.pad3);
        bc0 |= (c.x > thr1 && c.x == m0) ? (1u << t) : 0u;
        bc1 |= (c.y > thr1 && c.y == m1) ? (1u << t) : 0u;
        bc2 |= (c.z > thr1 && c.z == m2) ? (1u << t) : 0u;
        bc3 |= (c.w > thr1 && c.w == m3) ? (1u << t) : 0u;
    }
    const unsigned rowm = ((1u << RC) - 1u) << 3;
    unsigned e0 = bc0 & (bc0 << 1) & (bc0 >> 1);
    unsigned e1 = bc1 & (bc1 << 1) & (bc1 >> 1);
    unsigned e2 = bc2 & (bc2 << 1) & (bc2 >> 1);
    unsigned e3 = bc3 & (bc3 << 1) & (bc3 >> 1);
    unsigned o0 = e0 | (e0 << 1) | (e0 >> 1);
    unsigned o1_ = e1 | (e1 << 1) | (e1 >> 1);
    unsigned o2_ = e2 | (e2 << 1) | (e2 >> 1);
    unsigned o3_ = e3 | (e3 << 1) | (e3 >> 1);
    unsigned cnt1 = ((s.cmask & 1) ? __popc(o0  & rowm) : 0u)
                  + ((s.cmask & 2) ? __popc(o1_ & rowm) : 0u)
                  + ((s.cmask & 4) ? __popc(o2_ & rowm) : 0u)
                  + ((s.cmask & 8) ? __popc(o3_ & rowm) : 0u);

    // ---- orientation 2: bi2 bits over rows jj in [0,RC); horizontal 3-open ----
    unsigned d0 = 0, d1 = 0, d2 = 0, d3 = 0;
#pragma unroll
    for (int jj = 0; jj < RC; ++jj) {
        const int j = r0 + jj;
        const float rpad = (j < 3 || j > H - 4) ? 0.f : NEG_INF;
        float mx = fmax3(fmax3(cur[jj].x, cur[jj+1].x, cur[jj+2].x),
                         fmax3(cur[jj+3].x, cur[jj+4].x, cur[jj+5].x), cur[jj+6].x);
        float my = fmax3(fmax3(cur[jj].y, cur[jj+1].y, cur[jj+2].y),
                         fmax3(cur[jj+3].y, cur[jj+4].y, cur[jj+5].y), cur[jj+6].y);
        float mz = fmax3(fmax3(cur[jj].z, cur[jj+1].z, cur[jj+2].z),
                         fmax3(cur[jj+3].z, cur[jj+4].z, cur[jj+5].z), cur[jj+6].z);
        float mw = fmax3(fmax3(cur[jj].w, cur[jj+1].w, cur[jj+2].w),
                         fmax3(cur[jj+3].w, cur[jj+4].w, cur[jj+5].w), cur[jj+6].w);
        mx = fmaxf(mx, rpad); my = fmaxf(my, rpad);
        mz = fmaxf(mz, rpad); mw = fmaxf(mw, rpad);
        F4 ce = cur[jj + 3];
        d0 |= (ce.x > thr2 && ce.x == mx) ? (1u << jj) : 0u;
        d1 |= (ce.y > thr2 && ce.y == my) ? (1u << jj) : 0u;
        d2 |= (ce.z > thr2 && ce.z == mz) ? (1u << jj) : 0u;
        d3 |= (ce.w > thr2 && ce.w == mw) ? (1u << jj) : 0u;
    }
    const unsigned pz = __shfl_up(d2, 1), pw = __shfl_up(d3, 1);
    const unsigned n0 = __shfl_down(d0, 1), n1 = __shfl_down(d1, 1);
    const unsigned em1 = pz & pw & d0;
    const unsigned f0  = pw & d0 & d1;
    const unsigned f1  = d0 & d1 & d2;
    const unsigned f2  = d1 & d2 & d3;
    const unsigned f3  = d2 & d3 & n0;
    const unsigned fp4 = d3 & n0 & n1;
    const unsigned q0 = em1 | f0 | f1;
    const unsigned q1 = f0 | f1 | f2;
    const unsigned q2 = f1 | f2 | f3;
    const unsigned q3 = f2 | f3 | fp4;
    unsigned cnt2 = ((s.cmask & 1) ? __popc(q0) : 0u)
                  + ((s.cmask & 2) ? __popc(q1) : 0u)
                  + ((s.cmask & 4) ? __popc(q2) : 0u)
                  + ((s.cmask & 8) ? __popc(q3) : 0u);

    for (int off = 32; off > 0; off >>= 1) {
        cnt1 += __shfl_down(cnt1, off);
        cnt2 += __shfl_down(cnt2, off);
    }
    __shared__ unsigned sc1[4], sc2[4];
    if (lane == 0) { sc1[wid] = cnt1; sc2[wid] = cnt2; }
    __syncthreads();
    if (tid == 0) {
        const int blk = blk_id();
        cnts[blk]        = sc1[0] + sc1[1] + sc1[2] + sc1[3];
        cnts[NBLK + blk] = sc2[0] + sc2[1] + sc2[2] + sc2[3];
    }
}

__global__ void k_final(const unsigned int* __restrict__ cnts,
                        int* __restrict__ out) {
    const int tid = threadIdx.x;    // 256
    unsigned a = 0, c = 0;
    for (int i = tid; i < NBLK; i += 256) {
        a += cnts[i];
        c += cnts[NBLK + i];
    }
    for (int off = 32; off > 0; off >>= 1) {
        a += __shfl_down(a, off);
        c += __shfl_down(c, off);
    }
    __shared__ unsigned sa[4], sc[4];
    const int lane = tid & 63, wid = tid >> 6;
    if (lane == 0) { sa[wid] = a; sc[wid] = c; }
    __syncthreads();
    if (tid == 0) {
        unsigned A = sa[0] + sa[1] + sa[2] + sa[3];
        unsigned C = sc[0] + sc[1] + sc[2] + sc[3];
        out[0] = (A < C) ? 1 : 0;
    }
}

extern "C" void kernel_launch(void* const* d_in, const int* in_sizes, int n_in,
                              void* d_out, int out_size, void* d_ws, size_t ws_size,
                              hipStream_t stream) {
    const float* x = (const float*)d_in[0];
    int* out = (int*)d_out;
    double* sums = (double*)d_ws;                                 // 2*NBLK doubles
    float* thr = (float*)((char*)d_ws + 2 * NBLK * 8);            // 16 floats
    unsigned int* cnts = (unsigned int*)((char*)d_ws + 2 * NBLK * 8 + 256); // 2*NBLK uints

    k_sums  <<<dim3(9, GY, 8), 256, 0, stream>>>(x, sums);
    k_thr   <<<1, 256, 0, stream>>>(sums, thr);
    k_counts<<<dim3(9, GY, 8), 256, 0, stream>>>(x, thr, cnts);
    k_final <<<1, 256, 0, stream>>>(cnts, out);
}